// Round 2
// baseline (639.225 us; speedup 1.0000x reference)
//
#include <hip/hip_runtime.h>
#include <math.h>

// Problem constants
#define NB          16          // batches
#define NPB         (512*512)   // elements per batch
#define NBINS       64
#define GUARD       6           // window half-width -> guard rows each side
#define ROWS        (NBINS + 2*GUARD)   // 76 LDS rows per tensor
#define MM_BLOCKS   16          // min/max blocks per batch
#define HB          64          // hist blocks per batch
#define EPSF        1e-8f

// ---------- ordered-uint encoding for float atomic min/max ----------
__device__ __forceinline__ unsigned enc(float f) {
    unsigned u = __float_as_uint(f);
    return (u & 0x80000000u) ? ~u : (u | 0x80000000u);
}
__device__ __forceinline__ float dec(unsigned e) {
    return (e & 0x80000000u) ? __uint_as_float(e & 0x7fffffffu)
                             : __uint_as_float(~e);
}

// ws layout: [0..15] enc-min, [16..31] enc-max (uint), then float hist[2][16][64]
__global__ void init_ws(unsigned* mm, float* hist) {
    int t = threadIdx.x;
    if (t < 16)      mm[t] = 0xFFFFFFFFu;  // min sentinel (atomicMin)
    else if (t < 32) mm[t] = 0u;           // max sentinel (atomicMax)
    for (int i = t; i < 2 * NB * NBINS; i += 256) hist[i] = 0.0f;
}

// ---------- pass 1: per-batch min/max of target ----------
__global__ __launch_bounds__(256) void minmax_k(const float4* __restrict__ tgt,
                                                unsigned* __restrict__ mm) {
    const int batch = blockIdx.x / MM_BLOCKS;
    const int sub   = blockIdx.x % MM_BLOCKS;
    const int F4    = NPB / 4 / MM_BLOCKS;         // float4 per block
    const float4* p = tgt + (size_t)batch * (NPB / 4) + (size_t)sub * F4;

    float mn =  3.4e38f, mx = -3.4e38f;
    for (int i = threadIdx.x; i < F4; i += 256) {
        float4 v = p[i];
        mn = fminf(mn, fminf(fminf(v.x, v.y), fminf(v.z, v.w)));
        mx = fmaxf(mx, fmaxf(fmaxf(v.x, v.y), fmaxf(v.z, v.w)));
    }
    for (int o = 32; o; o >>= 1) {
        mn = fminf(mn, __shfl_down(mn, o));
        mx = fmaxf(mx, __shfl_down(mx, o));
    }
    __shared__ unsigned smn, smx;
    if (threadIdx.x == 0) { smn = 0xFFFFFFFFu; smx = 0u; }
    __syncthreads();
    if ((threadIdx.x & 63) == 0) {
        atomicMin(&smn, enc(mn));
        atomicMax(&smx, enc(mx));
    }
    __syncthreads();
    if (threadIdx.x == 0) {
        atomicMin(&mm[batch],      smn);
        atomicMax(&mm[16 + batch], smx);
    }
}

// ---------- pass 2: windowed soft histogram ----------
// kernel value for bin j at coord u (bin units): exp(-(u-j)^2/2)
// = A * r^k * C[k],  A=exp(-d^2/2), r=exp(d), d=u-j0, j=j0+k, C[k]=exp(-k^2/2)
// hcol points at (bin 0, this lane's column); guard rows above/below absorb
// the +/-6 window without any bounds checks (j0 clamped to [0,63]).
__device__ __forceinline__ void scatter(float x, float scale, float bias,
                                        float* __restrict__ hcol) {
    float u   = fmaf(x, scale, bias);          // continuous bin coordinate
    float j0f = rintf(u);
    j0f = fminf(fmaxf(j0f, 0.0f), 63.0f);
    int   j0  = (int)j0f;
    float d   = fminf(fmaxf(u - j0f, -20.0f), 20.0f);

    float A  = __expf(-0.5f * d * d);
    float r  = __expf(d);
    float ri = __expf(-d);

    float* hb = hcol + j0 * 64;                // stride 64 floats per row
    unsafeAtomicAdd(hb, A);
    float p = A;
    p *= r;  unsafeAtomicAdd(hb + 1*64, p * 0.60653066f);
    p *= r;  unsafeAtomicAdd(hb + 2*64, p * 0.13533528f);
    p *= r;  unsafeAtomicAdd(hb + 3*64, p * 0.011108997f);
    p *= r;  unsafeAtomicAdd(hb + 4*64, p * 3.3546263e-4f);
    p *= r;  unsafeAtomicAdd(hb + 5*64, p * 3.7266532e-6f);
    p *= r;  unsafeAtomicAdd(hb + 6*64, p * 1.5229980e-8f);
    p = A;
    p *= ri; unsafeAtomicAdd(hb - 1*64, p * 0.60653066f);
    p *= ri; unsafeAtomicAdd(hb - 2*64, p * 0.13533528f);
    p *= ri; unsafeAtomicAdd(hb - 3*64, p * 0.011108997f);
    p *= ri; unsafeAtomicAdd(hb - 4*64, p * 3.3546263e-4f);
    p *= ri; unsafeAtomicAdd(hb - 5*64, p * 3.7266532e-6f);
    p *= ri; unsafeAtomicAdd(hb - 6*64, p * 1.5229980e-8f);
}

__global__ __launch_bounds__(256) void hist_k(const float4* __restrict__ pred,
                                              const float4* __restrict__ tgt,
                                              const unsigned* __restrict__ mm,
                                              float* __restrict__ hist) {
    // lds[tensor][row][lane-column], row = bin + GUARD; column = tid&63
    // -> scatter bank = col%32, conflict-free (2-way alias is free)
    __shared__ float lds[2 * ROWS * 64];       // 38 KB
    const int batch = blockIdx.x / HB;
    const int sub   = blockIdx.x % HB;

    for (int i = threadIdx.x; i < 2 * ROWS * 64; i += 256) lds[i] = 0.0f;

    const float vmin  = dec(mm[batch]);
    const float vmax  = dec(mm[16 + batch]);
    const float denom = vmax - vmin + EPSF;
    const float scale = 64.0f / denom;
    const float bias  = fmaf(-vmin, scale, -0.5f);   // u = x*scale + bias
    __syncthreads();

    const int F4 = NPB / 4 / HB;               // 1024 float4 per block
    const size_t base = (size_t)batch * (NPB / 4) + (size_t)sub * F4;
    const int col = threadIdx.x & 63;
    float* h0 = lds + GUARD * 64 + col;                  // pred, bin-0 row
    float* h1 = lds + (ROWS + GUARD) * 64 + col;         // target, bin-0 row

    for (int i = threadIdx.x; i < F4; i += 256) {
        float4 a = pred[base + i];
        float4 b = tgt[base + i];
        scatter(a.x, scale, bias, h0);  scatter(a.y, scale, bias, h0);
        scatter(a.z, scale, bias, h0);  scatter(a.w, scale, bias, h0);
        scatter(b.x, scale, bias, h1);  scatter(b.y, scale, bias, h1);
        scatter(b.z, scale, bias, h1);  scatter(b.w, scale, bias, h1);
    }
    __syncthreads();

    // reduce 64 lane-columns per (tensor,bin); rotated access -> <=2-way alias
    const int t = threadIdx.x;
    if (t < 128) {
        const int tens = t >> 6, bin = t & 63;
        const float* row = lds + (tens * ROWS + bin + GUARD) * 64;
        float s = 0.0f;
        #pragma unroll
        for (int i = 0; i < 64; i++) s += row[(t + i) & 63];
        unsafeAtomicAdd(&hist[(tens * NB + batch) * NBINS + bin], s);
    }
}

// ---------- pass 3: KL in fp64 (tiny) ----------
__global__ void final_k(const float* __restrict__ hist, float* __restrict__ out) {
    const int lane = threadIdx.x;              // 64 threads = 64 bins
    double acc = 0.0;
    for (int b = 0; b < NB; b++) {
        double hp = (double)hist[b * NBINS + lane];
        double ht = (double)hist[(NB + b) * NBINS + lane];
        double sp = hp, st = ht;
        for (int o = 32; o; o >>= 1) {
            sp += __shfl_down(sp, o);
            st += __shfl_down(st, o);
        }
        sp = __shfl(sp, 0); st = __shfl(st, 0);
        double pp = hp / (sp + 1e-8);
        double pt = ht / (st + 1e-8);
        double term = pt * (log(pt + 1e-8) - log(pp + 1e-8));
        for (int o = 32; o; o >>= 1) term += __shfl_down(term, o);
        if (lane == 0) acc += term;
    }
    if (lane == 0) out[0] = (float)(0.1 * acc / (double)NB);
}

extern "C" void kernel_launch(void* const* d_in, const int* in_sizes, int n_in,
                              void* d_out, int out_size, void* d_ws, size_t ws_size,
                              hipStream_t stream) {
    const float* pred = (const float*)d_in[0];
    const float* tgt  = (const float*)d_in[1];
    unsigned* mm   = (unsigned*)d_ws;
    float*    hist = (float*)d_ws + 32;
    float*    out  = (float*)d_out;

    init_ws <<<1, 256, 0, stream>>>(mm, hist);
    minmax_k<<<NB * MM_BLOCKS, 256, 0, stream>>>((const float4*)tgt, mm);
    hist_k  <<<NB * HB, 256, 0, stream>>>((const float4*)pred, (const float4*)tgt, mm, hist);
    final_k <<<1, 64, 0, stream>>>(hist, out);
}

// Round 3
// 266.127 us; speedup vs baseline: 2.4020x; 2.4020x over previous
//
#include <hip/hip_runtime.h>
#include <math.h>

// Problem constants
#define NB          16          // batches
#define NPB         (512*512)   // elements per batch
#define NBINS       64
#define MM_BLOCKS   16          // min/max blocks per batch
#define CB          64          // chunks per (tensor,batch) -> grid = 2*16*64 = 2048
#define EPSF        1e-8f
#define CEXP        (-0.72134752044f)   // -0.5 * log2(e)

// ---------- ordered-uint encoding for float atomic min/max ----------
__device__ __forceinline__ unsigned enc(float f) {
    unsigned u = __float_as_uint(f);
    return (u & 0x80000000u) ? ~u : (u | 0x80000000u);
}
__device__ __forceinline__ float dec(unsigned e) {
    return (e & 0x80000000u) ? __uint_as_float(e & 0x7fffffffu)
                             : __uint_as_float(~e);
}

// wave-internal broadcast via VALU readlane (NOT the LDS pipe)
__device__ __forceinline__ float bcast(float x, int l) {
    return __int_as_float(__builtin_amdgcn_readlane(__float_as_int(x), l));
}

// ws layout: [0..15] enc-min, [16..31] enc-max (uint), then float hist[2][16][64]
__global__ void init_ws(unsigned* mm, float* hist) {
    int t = threadIdx.x;
    if (t < 16)      mm[t] = 0xFFFFFFFFu;  // min sentinel (atomicMin)
    else if (t < 32) mm[t] = 0u;           // max sentinel (atomicMax)
    for (int i = t; i < 2 * NB * NBINS; i += 256) hist[i] = 0.0f;
}

// ---------- pass 1: per-batch min/max of target ----------
__global__ __launch_bounds__(256) void minmax_k(const float4* __restrict__ tgt,
                                                unsigned* __restrict__ mm) {
    const int batch = blockIdx.x / MM_BLOCKS;
    const int sub   = blockIdx.x % MM_BLOCKS;
    const int F4    = NPB / 4 / MM_BLOCKS;         // float4 per block
    const float4* p = tgt + (size_t)batch * (NPB / 4) + (size_t)sub * F4;

    float mn =  3.4e38f, mx = -3.4e38f;
    for (int i = threadIdx.x; i < F4; i += 256) {
        float4 v = p[i];
        mn = fminf(mn, fminf(fminf(v.x, v.y), fminf(v.z, v.w)));
        mx = fmaxf(mx, fmaxf(fmaxf(v.x, v.y), fmaxf(v.z, v.w)));
    }
    for (int o = 32; o; o >>= 1) {
        mn = fminf(mn, __shfl_down(mn, o));
        mx = fmaxf(mx, __shfl_down(mx, o));
    }
    __shared__ unsigned smn, smx;
    if (threadIdx.x == 0) { smn = 0xFFFFFFFFu; smx = 0u; }
    __syncthreads();
    if ((threadIdx.x & 63) == 0) {
        atomicMin(&smn, enc(mn));
        atomicMax(&smx, enc(mx));
    }
    __syncthreads();
    if (threadIdx.x == 0) {
        atomicMin(&mm[batch],      smn);
        atomicMax(&mm[16 + batch], smx);
    }
}

// ---------- pass 2: dense gather histogram ----------
// Each wave owns all 64 bins (bin = lane). Points are read as float4 per lane,
// then broadcast across the wave with v_readlane. Per (point, bin-lane):
//   d = fma(x, scale, bias - bin);  acc += exp2(CEXP * d * d)
// Exact (no window truncation), no LDS/atomics in the hot loop.
__global__ __launch_bounds__(256) void hist_k(const float4* __restrict__ pred,
                                              const float4* __restrict__ tgt,
                                              const unsigned* __restrict__ mm,
                                              float* __restrict__ hist) {
    const int blk   = blockIdx.x;
    const int tens  = blk & 1;
    const int batch = (blk >> 1) & (NB - 1);
    const int chunk = blk >> 5;                    // 0..CB-1
    const int F4PB  = NPB / 4 / CB;                // 1024 float4 per block

    const float4* __restrict__ src =
        (tens ? tgt : pred) + (size_t)batch * (NPB / 4) + (size_t)chunk * F4PB;

    const float vmin  = dec(mm[batch]);
    const float vmax  = dec(mm[16 + batch]);
    const float denom = vmax - vmin + EPSF;
    const float scale = 64.0f / denom;
    const float bias  = fmaf(-vmin, scale, -0.5f); // u = x*scale + bias
    const int   wave  = threadIdx.x >> 6;
    const int   lane  = threadIdx.x & 63;
    const float blane = bias - (float)lane;        // fold bin into bias

    float acc = 0.0f;
    #pragma unroll
    for (int it = 0; it < F4PB / 256; ++it) {      // 4 iterations
        float4 v = src[it * 256 + threadIdx.x];
        #pragma unroll
        for (int l = 0; l < 64; ++l) {
            float x0 = bcast(v.x, l), x1 = bcast(v.y, l);
            float x2 = bcast(v.z, l), x3 = bcast(v.w, l);
            float d0 = fmaf(x0, scale, blane);
            float d1 = fmaf(x1, scale, blane);
            float d2 = fmaf(x2, scale, blane);
            float d3 = fmaf(x3, scale, blane);
            acc += exp2f(CEXP * d0 * d0);
            acc += exp2f(CEXP * d1 * d1);
            acc += exp2f(CEXP * d2 * d2);
            acc += exp2f(CEXP * d3 * d3);
        }
    }

    // block-level reduce (4 waves) then one global atomic per bin per block
    __shared__ float red[4][64];
    red[wave][lane] = acc;
    __syncthreads();
    if (wave == 0) {
        float s = red[0][lane] + red[1][lane] + red[2][lane] + red[3][lane];
        unsafeAtomicAdd(&hist[(tens * NB + batch) * NBINS + lane], s);
    }
}

// ---------- pass 3: KL in fp64 (tiny) ----------
__global__ void final_k(const float* __restrict__ hist, float* __restrict__ out) {
    const int lane = threadIdx.x;              // 64 threads = 64 bins
    double acc = 0.0;
    for (int b = 0; b < NB; b++) {
        double hp = (double)hist[b * NBINS + lane];
        double ht = (double)hist[(NB + b) * NBINS + lane];
        double sp = hp, st = ht;
        for (int o = 32; o; o >>= 1) {
            sp += __shfl_down(sp, o);
            st += __shfl_down(st, o);
        }
        sp = __shfl(sp, 0); st = __shfl(st, 0);
        double pp = hp / (sp + 1e-8);
        double pt = ht / (st + 1e-8);
        double term = pt * (log(pt + 1e-8) - log(pp + 1e-8));
        for (int o = 32; o; o >>= 1) term += __shfl_down(term, o);
        if (lane == 0) acc += term;
    }
    if (lane == 0) out[0] = (float)(0.1 * acc / (double)NB);
}

extern "C" void kernel_launch(void* const* d_in, const int* in_sizes, int n_in,
                              void* d_out, int out_size, void* d_ws, size_t ws_size,
                              hipStream_t stream) {
    const float* pred = (const float*)d_in[0];
    const float* tgt  = (const float*)d_in[1];
    unsigned* mm   = (unsigned*)d_ws;
    float*    hist = (float*)d_ws + 32;
    float*    out  = (float*)d_out;

    init_ws <<<1, 256, 0, stream>>>(mm, hist);
    minmax_k<<<NB * MM_BLOCKS, 256, 0, stream>>>((const float4*)tgt, mm);
    hist_k  <<<2 * NB * CB, 256, 0, stream>>>((const float4*)pred, (const float4*)tgt, mm, hist);
    final_k <<<1, 64, 0, stream>>>(hist, out);
}

// Round 4
// 153.180 us; speedup vs baseline: 4.1730x; 1.7373x over previous
//
#include <hip/hip_runtime.h>
#include <math.h>

// Problem constants
#define NB    16            // batches
#define NPB   (512*512)     // elements per batch
#define NBINS 64
#define MMB   16            // minmax blocks per batch
#define CB    32            // hist chunks per (tensor,batch) -> grid 2*16*32 = 1024
#define EPSF  1e-8f
#define QF    0.84932180517f   // sqrt(0.5*log2(e)); exp(-(u-k)^2/2) = exp2(-(q*u - q*k)^2)

// ws layout: mmn[256] | mmx[256] | hist[2][16][64]  (~10 KB)

// ---------- pass 1: per-batch block-level min/max (no atomics, no init kernel) ----------
// sub==0 blocks also zero this batch's hist slots (hist_k only runs after all
// minmax blocks complete, so this is race-free).
__global__ __launch_bounds__(256) void minmax_k(const float4* __restrict__ tgt,
                                                float* __restrict__ mmn,
                                                float* __restrict__ mmx,
                                                float* __restrict__ hist) {
    const int batch = blockIdx.x >> 4, sub = blockIdx.x & 15;
    if (sub == 0 && threadIdx.x < 128) {
        const int tens = threadIdx.x >> 6, lane = threadIdx.x & 63;
        hist[(tens * NB + batch) * NBINS + lane] = 0.0f;
    }
    const int F4 = NPB / 4 / MMB;              // 4096 float4 per block
    const float4* p = tgt + (size_t)batch * (NPB / 4) + (size_t)sub * F4;
    float mn = 3.4e38f, mx = -3.4e38f;
    for (int i = threadIdx.x; i < F4; i += 256) {
        float4 v = p[i];
        mn = fminf(mn, fminf(fminf(v.x, v.y), fminf(v.z, v.w)));
        mx = fmaxf(mx, fmaxf(fmaxf(v.x, v.y), fmaxf(v.z, v.w)));
    }
    #pragma unroll
    for (int o = 1; o < 64; o <<= 1) {
        mn = fminf(mn, __shfl_xor(mn, o));
        mx = fmaxf(mx, __shfl_xor(mx, o));
    }
    __shared__ float smn[4], smx[4];
    const int wave = threadIdx.x >> 6, lane = threadIdx.x & 63;
    if (lane == 0) { smn[wave] = mn; smx[wave] = mx; }
    __syncthreads();
    if (threadIdx.x == 0) {
        mmn[blockIdx.x] = fminf(fminf(smn[0], smn[1]), fminf(smn[2], smn[3]));
        mmx[blockIdx.x] = fmaxf(fmaxf(smx[0], smx[1]), fmaxf(smx[2], smx[3]));
    }
}

// ---------- pass 2: dense gather histogram, lane-owns-point ----------
// Each lane processes its own points; all 64 bins live in unrolled registers.
// Per (point,bin): v_sub(lit,k*q - u'), v_mul(-d,d), v_exp_f32, v_add — 3
// full-rate + 1 quarter-rate trans. No LDS, no readlane, no atomics in loop.
__global__ __launch_bounds__(256, 4) void hist_k(const float4* __restrict__ pred,
                                                 const float4* __restrict__ tgt,
                                                 const float* __restrict__ mmn,
                                                 const float* __restrict__ mmx,
                                                 float* __restrict__ hist) {
    const int blk   = blockIdx.x;
    const int tens  = blk & 1;
    const int batch = (blk >> 1) & (NB - 1);
    const int chunk = blk >> 5;

    // reduce the 16 per-block minmax partials (uniform scalar loads)
    float vmin = mmn[batch * MMB], vmax = mmx[batch * MMB];
    #pragma unroll
    for (int i = 1; i < MMB; ++i) {
        vmin = fminf(vmin, mmn[batch * MMB + i]);
        vmax = fmaxf(vmax, mmx[batch * MMB + i]);
    }
    const float denom   = vmax - vmin + EPSF;
    const float s64     = 64.0f / denom;
    const float scale_q = s64 * QF;
    const float bias_q  = fmaf(-vmin, s64, -0.5f) * QF;   // u' = q*(x*s64 - vmin*s64 - 0.5)

    const float4* __restrict__ src = (tens ? tgt : pred)
        + (size_t)batch * (NPB / 4) + (size_t)chunk * (NPB / 4 / CB);

    float acc[NBINS];
    #pragma unroll
    for (int k = 0; k < NBINS; ++k) acc[k] = 0.0f;

    for (int it = 0; it < (NPB / 4 / CB) / 256; ++it) {   // 8 iterations
        float4 v = src[it * 256 + threadIdx.x];
        float u0 = fmaf(v.x, scale_q, bias_q);
        float u1 = fmaf(v.y, scale_q, bias_q);
        float u2 = fmaf(v.z, scale_q, bias_q);
        float u3 = fmaf(v.w, scale_q, bias_q);
        #pragma unroll
        for (int k = 0; k < NBINS; ++k) {
            const float kq = (float)k * QF;               // compile-time literal
            float d0 = kq - u0, d1 = kq - u1, d2 = kq - u2, d3 = kq - u3;
            acc[k] += __builtin_amdgcn_exp2f(-(d0 * d0));
            acc[k] += __builtin_amdgcn_exp2f(-(d1 * d1));
            acc[k] += __builtin_amdgcn_exp2f(-(d2 * d2));
            acc[k] += __builtin_amdgcn_exp2f(-(d3 * d3));
        }
    }

    // epilogue: transpose-reduce acc[k] across the wave (bin k -> lane k)
    const int lane = threadIdx.x & 63, wave = threadIdx.x >> 6;
    float mine = 0.0f;
    #pragma unroll
    for (int k = 0; k < NBINS; ++k) {
        float v = acc[k];
        #pragma unroll
        for (int o = 1; o < 64; o <<= 1) v += __shfl_xor(v, o);
        if (lane == k) mine = v;
    }
    __shared__ float red[4][64];
    red[wave][lane] = mine;
    __syncthreads();
    if (wave == 0) {
        float s = red[0][lane] + red[1][lane] + red[2][lane] + red[3][lane];
        unsafeAtomicAdd(&hist[(tens * NB + batch) * NBINS + lane], s);
    }
}

// ---------- pass 3: KL in fp64, batches parallel across 4 waves ----------
__global__ __launch_bounds__(256) void final_k(const float* __restrict__ hist,
                                               float* __restrict__ out) {
    const int lane = threadIdx.x & 63, wave = threadIdx.x >> 6;
    __shared__ double wacc[4];
    double acc = 0.0;
    for (int b = wave; b < NB; b += 4) {
        double hp = (double)hist[b * NBINS + lane];
        double ht = (double)hist[(NB + b) * NBINS + lane];
        double sp = hp, st = ht;
        #pragma unroll
        for (int o = 1; o < 64; o <<= 1) {
            sp += __shfl_xor(sp, o);
            st += __shfl_xor(st, o);
        }
        double pp = hp / (sp + 1e-8);
        double pt = ht / (st + 1e-8);
        double term = pt * (log(pt + 1e-8) - log(pp + 1e-8));
        #pragma unroll
        for (int o = 1; o < 64; o <<= 1) term += __shfl_xor(term, o);
        acc += term;                                   // same on all lanes
    }
    if (lane == 0) wacc[wave] = acc;
    __syncthreads();
    if (threadIdx.x == 0)
        out[0] = (float)(0.1 * (wacc[0] + wacc[1] + wacc[2] + wacc[3]) / (double)NB);
}

extern "C" void kernel_launch(void* const* d_in, const int* in_sizes, int n_in,
                              void* d_out, int out_size, void* d_ws, size_t ws_size,
                              hipStream_t stream) {
    const float* pred = (const float*)d_in[0];
    const float* tgt  = (const float*)d_in[1];
    float* mmn  = (float*)d_ws;
    float* mmx  = mmn + NB * MMB;
    float* hist = mmx + NB * MMB;
    float* out  = (float*)d_out;

    minmax_k<<<NB * MMB, 256, 0, stream>>>((const float4*)tgt, mmn, mmx, hist);
    hist_k  <<<2 * NB * CB, 256, 0, stream>>>((const float4*)pred, (const float4*)tgt,
                                              mmn, mmx, hist);
    final_k <<<1, 256, 0, stream>>>(hist, out);
}

// Round 5
// 144.978 us; speedup vs baseline: 4.4091x; 1.0566x over previous
//
#include <hip/hip_runtime.h>
#include <math.h>

// Problem constants
#define NB    16            // batches
#define NPB   (512*512)     // elements per batch
#define NBINS 64
#define MMB   16            // minmax blocks per batch
#define CB    32            // hist chunks per (tensor,batch) -> grid 2*16*32 = 1024
#define EPSF  1e-8f
#define QF    0.84932180517f   // sqrt(0.5*log2(e)); exp(-d^2/2) = exp2(-(q*d)^2)
#define L2E   1.44269504089f   // log2(e)
#define INV_E 0.36787944117f   // e^-1

// ws layout: mmn[256] | mmx[256] | hist[2][16][64] | done(uint)

// ---------- pass 1: per-batch block-level min/max (also zeroes hist + done) ----------
__global__ __launch_bounds__(256) void minmax_k(const float4* __restrict__ tgt,
                                                float* __restrict__ mmn,
                                                float* __restrict__ mmx,
                                                float* __restrict__ hist,
                                                unsigned* __restrict__ done) {
    const int batch = blockIdx.x >> 4, sub = blockIdx.x & 15;
    if (sub == 0 && threadIdx.x < 128) {
        const int tens = threadIdx.x >> 6, lane = threadIdx.x & 63;
        hist[(tens * NB + batch) * NBINS + lane] = 0.0f;
    }
    if (blockIdx.x == 0 && threadIdx.x == 0) *done = 0u;

    const int F4 = NPB / 4 / MMB;              // 4096 float4 per block
    const float4* p = tgt + (size_t)batch * (NPB / 4) + (size_t)sub * F4;
    float mn = 3.4e38f, mx = -3.4e38f;
    for (int i = threadIdx.x; i < F4; i += 256) {
        float4 v = p[i];
        mn = fminf(mn, fminf(fminf(v.x, v.y), fminf(v.z, v.w)));
        mx = fmaxf(mx, fmaxf(fmaxf(v.x, v.y), fmaxf(v.z, v.w)));
    }
    #pragma unroll
    for (int o = 1; o < 64; o <<= 1) {
        mn = fminf(mn, __shfl_xor(mn, o));
        mx = fmaxf(mx, __shfl_xor(mx, o));
    }
    __shared__ float smn[4], smx[4];
    const int wave = threadIdx.x >> 6, lane = threadIdx.x & 63;
    if (lane == 0) { smn[wave] = mn; smx[wave] = mx; }
    __syncthreads();
    if (threadIdx.x == 0) {
        mmn[blockIdx.x] = fminf(fminf(smn[0], smn[1]), fminf(smn[2], smn[3]));
        mmx[blockIdx.x] = fmaxf(fmaxf(smx[0], smx[1]), fmaxf(smx[2], smx[3]));
    }
}

// ---------- pass 2: gather histogram w/ group-of-8 exp recurrence ----------
// Lane owns its points; 64 bin accumulators in registers. For bins k=8j..8j+7:
//   E(k) = exp(-(u-k)^2/2), recurrence E(k+1)=E(k)*G, G(k+1)=G(k)/e,
//   E re-anchored by a fresh exp2 at each group base (underflow safety).
// Last block to finish computes the KL (fp64) -> one fewer launch.
__global__ __launch_bounds__(256, 2) void hist_k(const float4* __restrict__ pred,
                                                 const float4* __restrict__ tgt,
                                                 const float* __restrict__ mmn,
                                                 const float* __restrict__ mmx,
                                                 float* __restrict__ hist,
                                                 unsigned* __restrict__ done,
                                                 float* __restrict__ out) {
    const int blk   = blockIdx.x;
    const int tens  = blk & 1;
    const int batch = (blk >> 1) & (NB - 1);
    const int chunk = blk >> 5;

    float vmin = mmn[batch * MMB], vmax = mmx[batch * MMB];
    #pragma unroll
    for (int i = 1; i < MMB; ++i) {
        vmin = fminf(vmin, mmn[batch * MMB + i]);
        vmax = fmaxf(vmax, mmx[batch * MMB + i]);
    }
    const float s64 = 64.0f / (vmax - vmin + EPSF);
    const float b0  = fmaf(-vmin, s64, -0.5f);       // u = x*s64 + b0 (bin coord)

    const float4* __restrict__ src = (tens ? tgt : pred)
        + (size_t)batch * (NPB / 4) + (size_t)chunk * (NPB / 4 / CB);

    float acc[NBINS];
    #pragma unroll
    for (int k = 0; k < NBINS; ++k) acc[k] = 0.0f;

    #pragma unroll 1
    for (int it = 0; it < (NPB / 4 / CB) / 256; ++it) {   // 8 iterations, body stays in I$
        float4 v = src[it * 256 + threadIdx.x];
        float u0 = fmaf(v.x, s64, b0), u1 = fmaf(v.y, s64, b0);
        float u2 = fmaf(v.z, s64, b0), u3 = fmaf(v.w, s64, b0);
        float q0 = u0 * QF, q1 = u1 * QF, q2 = u2 * QF, q3 = u3 * QF;
        // G = exp(u - 0.5) = 2^(u*L2E - 0.5*L2E)
        float G0 = __builtin_amdgcn_exp2f(fmaf(u0, L2E, -0.5f * L2E));
        float G1 = __builtin_amdgcn_exp2f(fmaf(u1, L2E, -0.5f * L2E));
        float G2 = __builtin_amdgcn_exp2f(fmaf(u2, L2E, -0.5f * L2E));
        float G3 = __builtin_amdgcn_exp2f(fmaf(u3, L2E, -0.5f * L2E));
        #pragma unroll
        for (int j = 0; j < 8; ++j) {
            const float c = (float)(8 * j) * QF;
            float d0 = q0 - c, d1 = q1 - c, d2 = q2 - c, d3 = q3 - c;
            float E0 = __builtin_amdgcn_exp2f(-(d0 * d0));
            float E1 = __builtin_amdgcn_exp2f(-(d1 * d1));
            float E2 = __builtin_amdgcn_exp2f(-(d2 * d2));
            float E3 = __builtin_amdgcn_exp2f(-(d3 * d3));
            #pragma unroll
            for (int i = 0; i < 8; ++i) {
                acc[8 * j + i] += (E0 + E1) + (E2 + E3);
                E0 *= G0; E1 *= G1; E2 *= G2; E3 *= G3;
                G0 *= INV_E; G1 *= INV_E; G2 *= INV_E; G3 *= INV_E;
            }
        }
    }

    // butterfly transpose-reduce: lane k ends holding sum over wave of acc[k]
    const int lane = threadIdx.x & 63, wave = threadIdx.x >> 6;
    {
        int len = 32;
        #pragma unroll
        for (int m = 32; m >= 1; m >>= 1) {
            const bool hi = (lane & m) != 0;
            #pragma unroll
            for (int i = 0; i < 32; ++i) {
                if (i < len) {
                    float keep = hi ? acc[i + len] : acc[i];
                    float send = hi ? acc[i] : acc[i + len];
                    acc[i] = keep + __shfl_xor(send, m);
                }
            }
            len >>= 1;
        }
    }
    __shared__ float red[4][64];
    red[wave][lane] = acc[0];
    __syncthreads();
    if (wave == 0) {
        float s = red[0][lane] + red[1][lane] + red[2][lane] + red[3][lane];
        unsafeAtomicAdd(&hist[(tens * NB + batch) * NBINS + lane], s);
    }

    // ---- last block computes the KL (fp64) ----
    __shared__ bool amlast;
    __syncthreads();
    if (threadIdx.x == 0) {
        __threadfence();
        amlast = (atomicAdd(done, 1u) == (unsigned)(gridDim.x - 1));
    }
    __syncthreads();
    if (amlast) {
        __threadfence();
        __shared__ double wacc[4];
        double a = 0.0;
        for (int b = wave; b < NB; b += 4) {
            float hpf = __hip_atomic_load(&hist[b * NBINS + lane],
                                          __ATOMIC_ACQUIRE, __HIP_MEMORY_SCOPE_AGENT);
            float htf = __hip_atomic_load(&hist[(NB + b) * NBINS + lane],
                                          __ATOMIC_ACQUIRE, __HIP_MEMORY_SCOPE_AGENT);
            double hp = (double)hpf, ht = (double)htf;
            double sp = hp, st = ht;
            #pragma unroll
            for (int o = 1; o < 64; o <<= 1) {
                sp += __shfl_xor(sp, o);
                st += __shfl_xor(st, o);
            }
            double pp = hp / (sp + 1e-8);
            double pt = ht / (st + 1e-8);
            double term = pt * (log(pt + 1e-8) - log(pp + 1e-8));
            #pragma unroll
            for (int o = 1; o < 64; o <<= 1) term += __shfl_xor(term, o);
            a += term;
        }
        if (lane == 0) wacc[wave] = a;
        __syncthreads();
        if (threadIdx.x == 0)
            out[0] = (float)(0.1 * (wacc[0] + wacc[1] + wacc[2] + wacc[3]) / (double)NB);
    }
}

extern "C" void kernel_launch(void* const* d_in, const int* in_sizes, int n_in,
                              void* d_out, int out_size, void* d_ws, size_t ws_size,
                              hipStream_t stream) {
    const float* pred = (const float*)d_in[0];
    const float* tgt  = (const float*)d_in[1];
    float*    mmn  = (float*)d_ws;
    float*    mmx  = mmn + NB * MMB;
    float*    hist = mmx + NB * MMB;
    unsigned* done = (unsigned*)(hist + 2 * NB * NBINS);
    float*    out  = (float*)d_out;

    minmax_k<<<NB * MMB, 256, 0, stream>>>((const float4*)tgt, mmn, mmx, hist, done);
    hist_k  <<<2 * NB * CB, 256, 0, stream>>>((const float4*)pred, (const float4*)tgt,
                                              mmn, mmx, hist, done, out);
}

// Round 6
// 140.792 us; speedup vs baseline: 4.5402x; 1.0297x over previous
//
#include <hip/hip_runtime.h>
#include <math.h>

// Problem constants
#define NB    16            // batches
#define NPB   (512*512)     // elements per batch
#define NBINS 64
#define MMB   16            // minmax blocks per batch
#define CB    32            // hist chunks per (tensor,batch) -> grid 2*16*32 = 1024
#define EPSF  1e-8f
#define QF    0.84932180517f   // sqrt(0.5*log2(e)); exp(-d^2/2) = exp2(-(q*d)^2)
#define L2E   1.44269504089f   // log2(e)
#define INV_E 0.36787944117f   // e^-1

// ws layout: mmn[256] | mmx[256] | hist[2][16][64] | done(uint)

// ---------- pass 1: per-batch block-level min/max (also zeroes hist + done) ----------
__global__ __launch_bounds__(256) void minmax_k(const float4* __restrict__ tgt,
                                                float* __restrict__ mmn,
                                                float* __restrict__ mmx,
                                                float* __restrict__ hist,
                                                unsigned* __restrict__ done) {
    const int batch = blockIdx.x >> 4, sub = blockIdx.x & 15;
    if (sub == 0 && threadIdx.x < 128) {
        const int tens = threadIdx.x >> 6, lane = threadIdx.x & 63;
        hist[(tens * NB + batch) * NBINS + lane] = 0.0f;
    }
    if (blockIdx.x == 0 && threadIdx.x == 0) *done = 0u;

    const int F4 = NPB / 4 / MMB;              // 4096 float4 per block
    const float4* p = tgt + (size_t)batch * (NPB / 4) + (size_t)sub * F4;
    float mn = 3.4e38f, mx = -3.4e38f;
    for (int i = threadIdx.x; i < F4; i += 256) {
        float4 v = p[i];
        mn = fminf(mn, fminf(fminf(v.x, v.y), fminf(v.z, v.w)));
        mx = fmaxf(mx, fmaxf(fmaxf(v.x, v.y), fmaxf(v.z, v.w)));
    }
    #pragma unroll
    for (int o = 1; o < 64; o <<= 1) {
        mn = fminf(mn, __shfl_xor(mn, o));
        mx = fmaxf(mx, __shfl_xor(mx, o));
    }
    __shared__ float smn[4], smx[4];
    const int wave = threadIdx.x >> 6, lane = threadIdx.x & 63;
    if (lane == 0) { smn[wave] = mn; smx[wave] = mx; }
    __syncthreads();
    if (threadIdx.x == 0) {
        mmn[blockIdx.x] = fminf(fminf(smn[0], smn[1]), fminf(smn[2], smn[3]));
        mmx[blockIdx.x] = fmaxf(fmaxf(smx[0], smx[1]), fmaxf(smx[2], smx[3]));
    }
}

// ---------- pass 2: gather histogram, bins split across waves ----------
// Wave w owns bins 16w..16w+15 (acc[16]/thread -> low VGPR -> 6 waves/SIMD).
// Every wave traverses the whole chunk (same stream -> L1 reuse).
// Group-of-8 recurrence: E(k+1)=E(k)*G(k), G(k+1)=G(k)/e, E re-anchored per
// group of 8 by a fresh exp2 (fp32 underflow then harmless).
// Last block to finish computes the KL in fp64 -> one fewer launch.
__global__ __launch_bounds__(256, 6) void hist_k(const float4* __restrict__ pred,
                                                 const float4* __restrict__ tgt,
                                                 const float* __restrict__ mmn,
                                                 const float* __restrict__ mmx,
                                                 float* __restrict__ hist,
                                                 unsigned* __restrict__ done,
                                                 float* __restrict__ out) {
    const int blk   = blockIdx.x;
    const int tens  = blk & 1;
    const int batch = (blk >> 1) & (NB - 1);
    const int chunk = blk >> 5;
    const int wave  = threadIdx.x >> 6, lane = threadIdx.x & 63;
    const int kbase = 16 * wave;               // this wave's first bin

    float vmin = mmn[batch * MMB], vmax = mmx[batch * MMB];
    #pragma unroll
    for (int i = 1; i < MMB; ++i) {
        vmin = fminf(vmin, mmn[batch * MMB + i]);
        vmax = fmaxf(vmax, mmx[batch * MMB + i]);
    }
    const float s64 = 64.0f / (vmax - vmin + EPSF);
    const float b0  = fmaf(-vmin, s64, -0.5f);       // u = x*s64 + b0 (bin coord)

    const int F4C = NPB / 4 / CB;                    // 2048 float4 per chunk
    const float4* __restrict__ src = (tens ? tgt : pred)
        + (size_t)batch * (NPB / 4) + (size_t)chunk * F4C;

    float acc[16];
    #pragma unroll
    for (int k = 0; k < 16; ++k) acc[k] = 0.0f;

    #pragma unroll 1
    for (int it = 0; it < F4C / 64; ++it) {          // 32 wave-iterations
        float4 v = src[it * 64 + lane];
        float u0 = fmaf(v.x, s64, b0), u1 = fmaf(v.y, s64, b0);
        float u2 = fmaf(v.z, s64, b0), u3 = fmaf(v.w, s64, b0);
        float q0 = u0 * QF, q1 = u1 * QF, q2 = u2 * QF, q3 = u3 * QF;
        // G at this wave's first bin: e^(u - kbase - 0.5)
        const float gb = -((float)kbase + 0.5f) * L2E;
        float G0 = __builtin_amdgcn_exp2f(fmaf(u0, L2E, gb));
        float G1 = __builtin_amdgcn_exp2f(fmaf(u1, L2E, gb));
        float G2 = __builtin_amdgcn_exp2f(fmaf(u2, L2E, gb));
        float G3 = __builtin_amdgcn_exp2f(fmaf(u3, L2E, gb));
        #pragma unroll
        for (int j = 0; j < 2; ++j) {                // 2 groups of 8 bins
            const float c = (float)(kbase + 8 * j) * QF;
            float d0 = q0 - c, d1 = q1 - c, d2 = q2 - c, d3 = q3 - c;
            float E0 = __builtin_amdgcn_exp2f(-(d0 * d0));
            float E1 = __builtin_amdgcn_exp2f(-(d1 * d1));
            float E2 = __builtin_amdgcn_exp2f(-(d2 * d2));
            float E3 = __builtin_amdgcn_exp2f(-(d3 * d3));
            #pragma unroll
            for (int i = 0; i < 8; ++i) {
                acc[8 * j + i] += (E0 + E1) + (E2 + E3);
                E0 *= G0; E1 *= G1; E2 *= G2; E3 *= G3;
                G0 *= INV_E; G1 *= INV_E; G2 *= INV_E; G3 *= INV_E;
            }
        }
    }

    // in-wave reduce: bins are disjoint across waves -> no cross-wave step
    #pragma unroll
    for (int i = 0; i < 16; ++i) {
        float v = acc[i];
        #pragma unroll
        for (int o = 1; o < 64; o <<= 1) v += __shfl_xor(v, o);
        if (lane == i) acc[0] = v;                   // lane i keeps bin kbase+i
    }
    if (lane < 16)
        unsafeAtomicAdd(&hist[(tens * NB + batch) * NBINS + kbase + lane], acc[0]);

    // ---- last block computes the KL (fp64) ----
    __shared__ bool amlast;
    __syncthreads();
    if (threadIdx.x == 0) {
        __threadfence();
        amlast = (atomicAdd(done, 1u) == (unsigned)(gridDim.x - 1));
    }
    __syncthreads();
    if (amlast) {
        __threadfence();
        __shared__ double wacc[4];
        double a = 0.0;
        for (int b = wave; b < NB; b += 4) {
            float hpf = __hip_atomic_load(&hist[b * NBINS + lane],
                                          __ATOMIC_ACQUIRE, __HIP_MEMORY_SCOPE_AGENT);
            float htf = __hip_atomic_load(&hist[(NB + b) * NBINS + lane],
                                          __ATOMIC_ACQUIRE, __HIP_MEMORY_SCOPE_AGENT);
            double hp = (double)hpf, ht = (double)htf;
            double sp = hp, st = ht;
            #pragma unroll
            for (int o = 1; o < 64; o <<= 1) {
                sp += __shfl_xor(sp, o);
                st += __shfl_xor(st, o);
            }
            double pp = hp / (sp + 1e-8);
            double pt = ht / (st + 1e-8);
            double term = pt * (log(pt + 1e-8) - log(pp + 1e-8));
            #pragma unroll
            for (int o = 1; o < 64; o <<= 1) term += __shfl_xor(term, o);
            a += term;
        }
        if (lane == 0) wacc[wave] = a;
        __syncthreads();
        if (threadIdx.x == 0)
            out[0] = (float)(0.1 * (wacc[0] + wacc[1] + wacc[2] + wacc[3]) / (double)NB);
    }
}

extern "C" void kernel_launch(void* const* d_in, const int* in_sizes, int n_in,
                              void* d_out, int out_size, void* d_ws, size_t ws_size,
                              hipStream_t stream) {
    const float* pred = (const float*)d_in[0];
    const float* tgt  = (const float*)d_in[1];
    float*    mmn  = (float*)d_ws;
    float*    mmx  = mmn + NB * MMB;
    float*    hist = mmx + NB * MMB;
    unsigned* done = (unsigned*)(hist + 2 * NB * NBINS);
    float*    out  = (float*)d_out;

    minmax_k<<<NB * MMB, 256, 0, stream>>>((const float4*)tgt, mmn, mmx, hist, done);
    hist_k  <<<2 * NB * CB, 256, 0, stream>>>((const float4*)pred, (const float4*)tgt,
                                              mmn, mmx, hist, done, out);
}